// Round 10
// baseline (290.494 us; speedup 1.0000x reference)
//
#include <hip/hip_runtime.h>
#include <hip/hip_bf16.h>

#define HW 16384   // 128*128

typedef unsigned short u16;
typedef unsigned int   u32;
typedef __attribute__((ext_vector_type(8))) short short8v;
typedef __attribute__((ext_vector_type(4))) float float4v;

__device__ __forceinline__ float b2f(u16 v) { return __uint_as_float((u32)v << 16); }
__device__ __forceinline__ u16 f2bf(float f) {   // RNE (cold paths)
  u32 u = __float_as_uint(f);
  u32 r = (u + 0x7fffu + ((u >> 16) & 1u)) >> 16;
  return (u16)r;
}
__device__ __forceinline__ float bflo(u32 u) { return __uint_as_float(u << 16); }
__device__ __forceinline__ float bfhi(u32 u) { return __uint_as_float(u & 0xffff0000u); }
// 1-instruction truncating pack: (hi16(b)<<16)|hi16(a)  [v_perm_b32]
__device__ __forceinline__ u32 pkt(float a, float b) {
  return __builtin_amdgcn_perm(__float_as_uint(b), __float_as_uint(a), 0x07060302u);
}
__device__ __forceinline__ u16 bft(float v) { return (u16)(__float_as_uint(v) >> 16); }  // trunc

// ---------------------------------------------------------------------------
// K0: swizzle ALL weights into MFMA-B fragment order (bf16, RNE).
//  B-frag layout: buf[((ntile*KS + ks)*64 + lane)*8 + j]
//  with o = ntile*16 + (lane&15), k = ks*32 + (lane>>4)*8 + j.
// ---------------------------------------------------------------------------
__global__ __launch_bounds__(256) void k_init(const float* __restrict__ w_dc,
                                              const float* __restrict__ w1,
                                              const float* __restrict__ w_ds,
                                              const float* __restrict__ w3,
                                              const float* __restrict__ w_off,
                                              u16* __restrict__ wTb, u16* __restrict__ wB1,
                                              u16* __restrict__ w3b, u16* __restrict__ woffb) {
  int idx = blockIdx.x * 256 + threadIdx.x;
  if (idx < 147456) {
    int ntile = idx / 18432, r = idx % 18432;
    int ks = r / 512, r2 = r % 512;
    int lane = r2 / 8, j = r2 % 8;
    int o = ntile * 16 + (lane & 15);
    int k = ks * 32 + ((lane >> 4) * 8) + j;
    int tap = k >> 7, ci = k & 127;
    wTb[idx] = f2bf(w_dc[(o * 128 + ci) * 9 + tap]);
  }
  int i1 = idx - 147456;
  if (i1 >= 0 && i1 < 65536) {
    int ntile = i1 / 4096, r = i1 % 4096;
    int ks = r / 512, r2 = r % 512;
    int lane = r2 / 8, j = r2 % 8;
    int o = ntile * 16 + (lane & 15);
    int c = ks * 32 + ((lane >> 4) * 8) + j;
    float v = (ntile < 8) ? w1[o * 256 + c] : w_ds[(o - 128) * 256 + c];
    wB1[i1] = f2bf(v);
  }
  int i2 = idx - 212992;
  if (i2 >= 0 && i2 < 16384) {
    int ntile = i2 / 2048, r = i2 % 2048;
    int ks = r / 512, r2 = r % 512;
    int lane = r2 / 8, j = r2 % 8;
    int o = ntile * 16 + (lane & 15);
    int c = ks * 32 + ((lane >> 4) * 8) + j;
    w3b[i2] = f2bf(w3[o * 128 + c]);
  }
  int i3 = idx - 229376;
  if (i3 >= 0 && i3 < 36864) {
    int ntile = i3 / 18432, r = i3 % 18432;
    int ks = r / 512, r2 = r % 512;
    int lane = r2 / 8, j = r2 % 8;
    int oc = ntile * 16 + (lane & 15);
    int k = ks * 32 + ((lane >> 4) * 8) + j;
    int tap = k >> 7, c = k & 127;
    woffb[i3] = (oc < 27) ? f2bf(w_off[oc * 1152 + c * 9 + tap]) : (u16)0;
  }
}

// ---------------------------------------------------------------------------
// K1 v3: fused conv1+downsample MFMA GEMM. M=32, N=256, K=256.
//  (proven; unchanged from R9) grid (4,128,4); block 256 = 4 waves.
// ---------------------------------------------------------------------------
__global__ __launch_bounds__(256) void k_fused1(const float* __restrict__ x,
                                                const u16* __restrict__ wB1,
                                                const float* __restrict__ s1a, const float* __restrict__ t1a,
                                                const float* __restrict__ s1b, const float* __restrict__ t1b,
                                                const float* __restrict__ b_ds,
                                                const float* __restrict__ sd, const float* __restrict__ td,
                                                u16* __restrict__ out1,      // [b][h][w][o]
                                                u16* __restrict__ identb)    // [b][o][h][w]
{
  __shared__ __align__(16) u16 xA[8704];
  const int tid = threadIdx.x;
  const int wq = blockIdx.x, h = blockIdx.y, b = blockIdx.z;
  const int wave = tid >> 6, lane = tid & 63;

  {
    const float* xb = x + (size_t)b * 256 * HW + h * 128 + wq * 32;
    u32* dst = (u32*)xA;                 // u32 pitch 133 per pos row
    int cp = tid >> 3, wg = tid & 7;
#pragma unroll
    for (int i = 0; i < 4; ++i) {
      int cpair = i * 32 + cp;           // 0..127
      int c0 = cpair * 2;
      float4 va = *(const float4*)&xb[(size_t)c0 * HW + wg * 4];
      float4 vb = *(const float4*)&xb[(size_t)(c0 + 1) * HW + wg * 4];
      int p0 = wg * 4;
      dst[(p0 + 0) * 133 + cpair] = pkt(va.x, vb.x);
      dst[(p0 + 1) * 133 + cpair] = pkt(va.y, vb.y);
      dst[(p0 + 2) * 133 + cpair] = pkt(va.z, vb.z);
      dst[(p0 + 3) * 133 + cpair] = pkt(va.w, vb.w);
    }
  }
  __syncthreads();

  const int nlo = lane & 15, kgr = lane >> 4;
  float4v acc[2][4];
#pragma unroll
  for (int mt = 0; mt < 2; ++mt)
#pragma unroll
    for (int nt = 0; nt < 4; ++nt) acc[mt][nt] = (float4v)(0.f);

  const u16* a0p = &xA[nlo * 266 + kgr * 8];
  const u16* a1p = &xA[(nlo + 16) * 266 + kgr * 8];
  const u16* bp = &wB1[(((size_t)(wave * 4) * 8) * 64 + lane) * 8];

#pragma unroll
  for (int ks = 0; ks < 8; ++ks) {
    short8v a0 = *(const short8v*)(a0p + ks * 32);
    short8v a1 = *(const short8v*)(a1p + ks * 32);
#pragma unroll
    for (int nt = 0; nt < 4; ++nt) {
      short8v bv = *(const short8v*)(bp + nt * 4096 + ks * 512);
      acc[0][nt] = __builtin_amdgcn_mfma_f32_16x16x32_bf16(a0, bv, acc[0][nt], 0, 0, 0);
      acc[1][nt] = __builtin_amdgcn_mfma_f32_16x16x32_bf16(a1, bv, acc[1][nt], 0, 0, 0);
    }
  }
  __syncthreads();   // xA dead; reuse as P1 + T1

  u16* P1 = xA;              // [pos][136]
  u16* T1 = xA + 4352;       // [o][34]

  const int rbase = kgr * 4;
  if (wave < 2) {
#pragma unroll
    for (int nt = 0; nt < 4; ++nt) {
      int o = (wave * 4 + nt) * 16 + nlo;
      float sa = s1a[o], ta = t1a[o], sb = s1b[o], tb = t1b[o];
#pragma unroll
      for (int mt = 0; mt < 2; ++mt)
#pragma unroll
        for (int r = 0; r < 4; ++r) {
          float v = acc[mt][nt][r];
          v = fmaxf(sa * v + ta, 0.f);
          v = fmaxf(sb * v + tb, 0.f);
          int pos = mt * 16 + rbase + r;
          P1[pos * 136 + o] = bft(v);
        }
    }
  } else {
#pragma unroll
    for (int nt = 0; nt < 4; ++nt) {
      int og = (wave * 4 + nt) * 16 + nlo - 128;
      float sv = sd[og], tv = td[og], bv = b_ds[og];
#pragma unroll
      for (int mt = 0; mt < 2; ++mt)
#pragma unroll
        for (int r = 0; r < 4; ++r) {
          float v = sv * (acc[mt][nt][r] + bv) + tv;
          T1[og * 34 + mt * 16 + rbase + r] = bft(v);
        }
    }
  }
  __syncthreads();

  // ---- out1: fully-coalesced uint4 stores ----
  {
    size_t rowbase = ((size_t)((b * 128 + h) * 128 + wq * 32)) * 128;
#pragma unroll
    for (int i = 0; i < 2; ++i) {
      int s = i * 256 + tid;             // 0..511
      int pos = s >> 4, q = s & 15;
      uint4 v = *(const uint4*)&P1[pos * 136 + q * 8];
      *(uint4*)&out1[rowbase + (size_t)pos * 128 + q * 8] = v;
    }
  }
  // ---- identb: transpose store ----
  {
    int o = tid >> 1, half = tid & 1;
    const u16* src = &T1[o * 34 + half * 16];
    u32 bb[8];
#pragma unroll
    for (int i = 0; i < 8; ++i) bb[i] = *(const u32*)(src + i * 2);
    size_t g = ((size_t)((b * 128 + o) * 128 + h)) * 128 + wq * 32 + half * 16;
    *(uint4*)&identb[g] = make_uint4(bb[0], bb[1], bb[2], bb[3]);
    *(uint4*)&identb[g + 8] = make_uint4(bb[4], bb[5], bb[6], bb[7]);
  }
}

// ---------------------------------------------------------------------------
// K2: MEGA-FUSED DCNv2, v9 = v8 + three occupancy/latency levers:
//  (1) LDS diet 44.2->35.1 KB => 4 blocks/CU (32 waves ceiling):
//      A2 re-split (ntile x mt x kg2) halves offp to 8 KB;
//      reduction in 4 stages halves Pp to 16 KB.
//  (2) XCD-chunked block swizzle: nid=(flat%8)*256+flat/8 (bijective) =>
//      each XCD owns 64 consecutive h of one batch; out1 working set
//      ~2.1 MB < 4 MB XCD-L2 => corner gathers L2-hit.
//  (3) s_setprio(1) around loop-B MFMA cluster (barrier-free loop => wave
//      role diversity => T5 favorable regime).
//  grid (4,128,4); block 512.
// ---------------------------------------------------------------------------
__global__ __launch_bounds__(512) void k_dcn(const u16* __restrict__ out1,
                                             const u16* __restrict__ wTb,
                                             const u16* __restrict__ w3b,
                                             const u16* __restrict__ woffb,
                                             const float* __restrict__ b_off,
                                             const float* __restrict__ b_dc,
                                             const float* __restrict__ s2, const float* __restrict__ t2,
                                             const float* __restrict__ s3a, const float* __restrict__ t3a,
                                             const float* __restrict__ s3b, const float* __restrict__ t3b,
                                             const u16* __restrict__ identb,
                                             float* __restrict__ out) {
  // Overlay map (35,936 B):
  //  A-phase : W [0,27744) = 102 rows x 136 u16 ; offp [27744,35936) 2x32x32 f32
  //  A3/loopB: jobtab Jl [0,9216) = 288 jobs x 8 u32   (W dead after A2)
  //  reduce  : P [0,8704) 32x136 u16 ; Pp [9216,25600) 4096 f32
  //  conv3   : P + T2 [9216,26112) 128x33 f32          (Pp dead)
  __shared__ __align__(16) u16 U[17968];

  u16*   W    = U;                                  // pitch 136 u16
  float* offp = (float*)((char*)U + 27744);         // [kg2][pos32][oc32]
  u32*   Jl   = (u32*)U;                            // jobtab
  float* Pp   = (float*)((char*)U + 9216);          // [mh][ks][r4][o128]
  u16*   P    = U;                                  // [pos32][136]
  float* T2   = (float*)((char*)U + 9216);          // [o][33]

  const int tid = threadIdx.x;
  // XCD-chunked bijective swizzle (2048 blocks, 8 XCDs, 2048%8==0)
  const int flat = blockIdx.x + (blockIdx.y << 2) + (blockIdx.z << 9);
  const int nid = (flat & 7) * 256 + (flat >> 3);
  const int wq = nid & 3, h = (nid >> 2) & 127, b = nid >> 9;
  const int wave = tid >> 6, lane = tid & 63;
  const int nlo = lane & 15, kgr = lane >> 4;
  const u16* base = out1 + (size_t)b * HW * 128;
  const int w0 = wq * 32;

  // ---- A1: stage window rows h-1..h+1, cols w0-1..w0+32 (102 px) ----
  for (int k = tid; k < 6528; k += 512) {           // 102 px * 64 u32
    int pix = k >> 6, cp = k & 63;
    int seg = pix / 34, col = pix % 34;
    int y = h - 1 + seg, x = w0 - 1 + col;
    u32 v = 0;
    if ((y >= 0) & (y < 128) & (x >= 0) & (x < 128))
      v = *(const u32*)&base[((size_t)(y * 128 + x)) * 128 + cp * 2];
    *((u32*)W + pix * 68 + cp) = v;
  }
  __syncthreads();

  // ---- A2: offset conv, 9 taps; 8 waves = ntile(2) x mt(2) x kg(2) ----
  {
    const int ntile = wave & 1, mt = (wave >> 1) & 1, kg = wave >> 2;
    const int t0 = kg ? 5 : 0, t1 = kg ? 9 : 5;
    float4v oacc = (float4v)(0.f);
    for (int t = t0; t < t1; ++t) {
      int ty = t / 3, tx = t % 3;
      const u16* bp = &woffb[(((size_t)(ntile * 36 + t * 4)) * 64 + lane) * 8];
      const u16* ap = &W[(ty * 34 + mt * 16 + nlo + tx) * 136 + kgr * 8];
#pragma unroll
      for (int ksl = 0; ksl < 4; ++ksl) {
        short8v bv = *(const short8v*)(bp + ksl * 512);
        short8v a = *(const short8v*)(ap + ksl * 32);
        oacc = __builtin_amdgcn_mfma_f32_16x16x32_bf16(a, bv, oacc, 0, 0, 0);
      }
    }
    int oc = ntile * 16 + nlo;
#pragma unroll
    for (int r = 0; r < 4; ++r)
      offp[kg * 1024 + (mt * 16 + kgr * 4 + r) * 32 + oc] = oacc[r];
  }
  __syncthreads();

  // ---- A3: per-job clamped corner offsets + weights -> jobtab ----
  if (tid < 288) {
    int pos = tid / 9, tap = tid % 9;
    int w = w0 + pos;
    float dy  = offp[pos * 32 + tap]      + offp[1024 + pos * 32 + tap]      + b_off[tap];
    float dxv = offp[pos * 32 + 9 + tap]  + offp[1024 + pos * 32 + 9 + tap]  + b_off[9 + tap];
    float sg  = offp[pos * 32 + 18 + tap] + offp[1024 + pos * 32 + 18 + tap] + b_off[18 + tap];
    float mk = 1.f / (1.f + __expf(-sg));
    float py = (float)(h - 1 + tap / 3) + dy;
    float px = (float)(w - 1 + tap % 3) + dxv;
    float fy = floorf(py), fx = floorf(px);
    int y0 = (int)fy, x0 = (int)fx;
    float wy = py - fy, wxf = px - fx;
    bool vy0 = (y0 >= 0) & (y0 < 128), vy1 = (y0 >= -1) & (y0 < 127);
    bool vx0 = (x0 >= 0) & (x0 < 128), vx1 = (x0 >= -1) & (x0 < 127);
    float w00 = (vy0 & vx0) ? (1.f - wy) * (1.f - wxf) * mk : 0.f;
    float w01 = (vy0 & vx1) ? (1.f - wy) * wxf * mk : 0.f;
    float w10 = (vy1 & vx0) ? wy * (1.f - wxf) * mk : 0.f;
    float w11 = (vy1 & vx1) ? wy * wxf * mk : 0.f;
    int y0c = min(max(y0, 0), 127), y1c = min(max(y0 + 1, 0), 127);
    int x0c = min(max(x0, 0), 127), x1c = min(max(x0 + 1, 0), 127);
    u32* jt = &Jl[tid * 8];
    jt[0] = (u32)((y0c * 128 + x0c) * 128);
    jt[1] = (u32)((y0c * 128 + x1c) * 128);
    jt[2] = (u32)((y1c * 128 + x0c) * 128);
    jt[3] = (u32)((y1c * 128 + x1c) * 128);
    ((float*)jt)[4] = w00; ((float*)jt)[5] = w01;
    ((float*)jt)[6] = w10; ((float*)jt)[7] = w11;
  }
  __syncthreads();

  // ---- Loop B: DCN conv, K-split, barrier-free (v8-proven) + setprio ----
  float4v acc8[8];
#pragma unroll
  for (int nt = 0; nt < 8; ++nt) acc8[nt] = (float4v)(0.f);
  {
    const int ks = wave & 3, mh = wave >> 2;
    const int ch0 = ks * 32 + kgr * 8;      // this lane's 8-channel group
    const int jrow = (mh * 16 + nlo) * 9;   // jobs of this lane's pos

    u32 gA[16], gB[16];
    float4 wA, wB;
    {
      uint4 co = *(const uint4*)&Jl[jrow * 8];
      wA = *(const float4*)&Jl[jrow * 8 + 4];
      uint4 v0 = *(const uint4*)(base + co.x + ch0);
      uint4 v1 = *(const uint4*)(base + co.y + ch0);
      uint4 v2 = *(const uint4*)(base + co.z + ch0);
      uint4 v3 = *(const uint4*)(base + co.w + ch0);
      gA[0] = v0.x; gA[1] = v0.y; gA[2] = v0.z; gA[3] = v0.w;
      gA[4] = v1.x; gA[5] = v1.y; gA[6] = v1.z; gA[7] = v1.w;
      gA[8] = v2.x; gA[9] = v2.y; gA[10] = v2.z; gA[11] = v2.w;
      gA[12] = v3.x; gA[13] = v3.y; gA[14] = v3.z; gA[15] = v3.w;
    }
#pragma unroll
    for (int t = 0; t < 9; ++t) {
      if (t < 8) {
        uint4 co = *(const uint4*)&Jl[(jrow + t + 1) * 8];
        if ((t & 1) == 0) {
          wB = *(const float4*)&Jl[(jrow + t + 1) * 8 + 4];
          uint4 v0 = *(const uint4*)(base + co.x + ch0);
          uint4 v1 = *(const uint4*)(base + co.y + ch0);
          uint4 v2 = *(const uint4*)(base + co.z + ch0);
          uint4 v3 = *(const uint4*)(base + co.w + ch0);
          gB[0] = v0.x; gB[1] = v0.y; gB[2] = v0.z; gB[3] = v0.w;
          gB[4] = v1.x; gB[5] = v1.y; gB[6] = v1.z; gB[7] = v1.w;
          gB[8] = v2.x; gB[9] = v2.y; gB[10] = v2.z; gB[11] = v2.w;
          gB[12] = v3.x; gB[13] = v3.y; gB[14] = v3.z; gB[15] = v3.w;
        } else {
          wA = *(const float4*)&Jl[(jrow + t + 1) * 8 + 4];
          uint4 v0 = *(const uint4*)(base + co.x + ch0);
          uint4 v1 = *(const uint4*)(base + co.y + ch0);
          uint4 v2 = *(const uint4*)(base + co.z + ch0);
          uint4 v3 = *(const uint4*)(base + co.w + ch0);
          gA[0] = v0.x; gA[1] = v0.y; gA[2] = v0.z; gA[3] = v0.w;
          gA[4] = v1.x; gA[5] = v1.y; gA[6] = v1.z; gA[7] = v1.w;
          gA[8] = v2.x; gA[9] = v2.y; gA[10] = v2.z; gA[11] = v2.w;
          gA[12] = v3.x; gA[13] = v3.y; gA[14] = v3.z; gA[15] = v3.w;
        }
      }
      union { u32 u[4]; short8v s; } av;
      {
        const u32* g = ((t & 1) == 0) ? gA : gB;
        float4 w = ((t & 1) == 0) ? wA : wB;
#pragma unroll
        for (int p = 0; p < 4; ++p) {
          float alo = w.x * bflo(g[p])      + w.y * bflo(g[4 + p])
                    + w.z * bflo(g[8 + p])  + w.w * bflo(g[12 + p]);
          float ahi = w.x * bfhi(g[p])      + w.y * bfhi(g[4 + p])
                    + w.z * bfhi(g[8 + p])  + w.w * bfhi(g[12 + p]);
          av.u[p] = pkt(alo, ahi);
        }
      }
      {
        const u16* bb = &wTb[(((size_t)(t * 4 + ks)) * 64 + lane) * 8];
        __builtin_amdgcn_s_setprio(1);
#pragma unroll
        for (int nt = 0; nt < 8; ++nt) {
          short8v bv = *(const short8v*)(bb + (size_t)nt * 18432);
          acc8[nt] = __builtin_amdgcn_mfma_f32_16x16x32_bf16(av.s, bv, acc8[nt], 0, 0, 0);
        }
        __builtin_amdgcn_s_setprio(0);
      }
    }
  }
  __syncthreads();   // jobtab dead; U reusable

  // ---- Reduction: 4 stages x 4 pos; combine 4 K-partials + bn2 -> P ----
  {
    const int ks = wave & 3, mh = wave >> 2;
#pragma unroll
    for (int s = 0; s < 4; ++s) {
      if (kgr == s) {
#pragma unroll
        for (int nt = 0; nt < 8; ++nt)
#pragma unroll
          for (int r = 0; r < 4; ++r)
            Pp[mh * 2048 + ks * 512 + r * 128 + nt * 16 + nlo] = acc8[nt][r];
      }
      __syncthreads();
#pragma unroll
      for (int q = 0; q < 2; ++q) {
        int idx = q * 512 + tid;
        int mi = idx >> 9, rem = idx & 511;
        int p = rem >> 7, o = rem & 127;
        const float* Pb = Pp + mi * 2048 + p * 128 + o;
        float sv = Pb[0] + Pb[512] + Pb[1024] + Pb[1536];
        float v = sv + b_dc[o];
        v = fmaxf(s2[o] * v + t2[o], 0.f);
        P[(mi * 16 + s * 4 + p) * 136 + o] = bft(v);
      }
      __syncthreads();
    }
  }

  // ---- conv3 MFMA (M=32, K=128): wave owns o-tile = wave, both m-tiles ----
  float4v acc2[2];
  acc2[0] = (float4v)(0.f); acc2[1] = (float4v)(0.f);
  {
    const u16* bp3 = &w3b[(((size_t)(wave * 4)) * 64 + lane) * 8];
#pragma unroll
    for (int ks3 = 0; ks3 < 4; ++ks3) {
      short8v bv = *(const short8v*)(bp3 + ks3 * 512);
#pragma unroll
      for (int mt = 0; mt < 2; ++mt) {
        short8v a = *(const short8v*)&P[(mt * 16 + nlo) * 136 + ks3 * 32 + kgr * 8];
        acc2[mt] = __builtin_amdgcn_mfma_f32_16x16x32_bf16(a, bv, acc2[mt], 0, 0, 0);
      }
    }
  }

  // bn3 chain -> T2[o][pos33] (overlays dead Pp; P region disjoint)
  {
    int o = wave * 16 + nlo;
    float sa = s3a[o], ta = t3a[o], sb = s3b[o], tb = t3b[o];
#pragma unroll
    for (int mt = 0; mt < 2; ++mt)
#pragma unroll
      for (int r = 0; r < 4; ++r) {
        float v = acc2[mt][r];
        v = fmaxf(sa * v + ta, 0.f);
        v = sb * v + tb;
        T2[o * 33 + mt * 16 + kgr * 4 + r] = v;
      }
  }
  __syncthreads();

  // ---- transpose + ident + relu -> out NCHW fp32 ----
  {
    int o = tid >> 2, qd = tid & 3;
    size_t g = ((size_t)((b * 128 + o) * 128 + h)) * 128 + w0 + qd * 8;
    const float* trow = &T2[o * 33 + qd * 8];
    uint4 iv = *(const uint4*)&identb[g];
    u32 iw[4] = {iv.x, iv.y, iv.z, iv.w};
    float4 ov[2];
#pragma unroll
    for (int q = 0; q < 2; ++q) {
      float r0 = trow[q * 4 + 0] + bflo(iw[q * 2]);
      float r1 = trow[q * 4 + 1] + bfhi(iw[q * 2]);
      float r2 = trow[q * 4 + 2] + bflo(iw[q * 2 + 1]);
      float r3 = trow[q * 4 + 3] + bfhi(iw[q * 2 + 1]);
      ov[q] = make_float4(fmaxf(r0, 0.f), fmaxf(r1, 0.f), fmaxf(r2, 0.f), fmaxf(r3, 0.f));
    }
    *(float4*)&out[g] = ov[0];
    *(float4*)&out[g + 4] = ov[1];
  }
}

// ---------------------------------------------------------------------------
extern "C" void kernel_launch(void* const* d_in, const int* in_sizes, int n_in,
                              void* d_out, int out_size, void* d_ws, size_t ws_size,
                              hipStream_t stream) {
  const float* x     = (const float*)d_in[0];
  const float* w1    = (const float*)d_in[1];
  const float* s1a   = (const float*)d_in[2];
  const float* t1a   = (const float*)d_in[3];
  const float* s1b   = (const float*)d_in[4];
  const float* t1b   = (const float*)d_in[5];
  const float* w_off = (const float*)d_in[6];
  const float* b_off = (const float*)d_in[7];
  const float* w_dc  = (const float*)d_in[8];
  const float* b_dc  = (const float*)d_in[9];
  const float* s2    = (const float*)d_in[10];
  const float* t2    = (const float*)d_in[11];
  const float* w3    = (const float*)d_in[12];
  const float* s3a   = (const float*)d_in[13];
  const float* t3a   = (const float*)d_in[14];
  const float* s3b   = (const float*)d_in[15];
  const float* t3b   = (const float*)d_in[16];
  const float* w_ds  = (const float*)d_in[17];
  const float* b_ds  = (const float*)d_in[18];
  const float* sd    = (const float*)d_in[19];
  const float* td    = (const float*)d_in[20];

  char* ws = (char*)d_ws;
  u16* wTb    = (u16*)(ws + 0);            //    294,912 B
  u16* wB1    = (u16*)(ws + 294912);       //    131,072 B
  u16* w3b    = (u16*)(ws + 425984);       //     32,768 B
  u16* woffb  = (u16*)(ws + 458752);       //     73,728 B
  u16* out1   = (u16*)(ws + 532480);       // 16,777,216 B  NHWC bf16
  u16* identb = (u16*)(ws + 17309696);     // 16,777,216 B  NCHW bf16

  k_init  <<<1040, 256, 0, stream>>>(w_dc, w1, w_ds, w3, w_off, wTb, wB1, w3b, woffb);
  k_fused1<<<dim3(4, 128, 4), 256, 0, stream>>>(x, wB1, s1a, t1a, s1b, t1b, b_ds, sd, td, out1, identb);
  k_dcn   <<<dim3(4, 128, 4), 512, 0, stream>>>(out1, wTb, w3b, woffb, b_off, b_dc, s2, t2,
                                                s3a, t3a, s3b, t3b, identb, (float*)d_out);
}

// Round 11
// 244.542 us; speedup vs baseline: 1.1879x; 1.1879x over previous
//
#include <hip/hip_runtime.h>
#include <hip/hip_bf16.h>

#define HW 16384   // 128*128

typedef unsigned short u16;
typedef unsigned int   u32;
typedef __attribute__((ext_vector_type(8))) short short8v;
typedef __attribute__((ext_vector_type(4))) float float4v;

__device__ __forceinline__ float b2f(u16 v) { return __uint_as_float((u32)v << 16); }
__device__ __forceinline__ u16 f2bf(float f) {   // RNE (cold paths)
  u32 u = __float_as_uint(f);
  u32 r = (u + 0x7fffu + ((u >> 16) & 1u)) >> 16;
  return (u16)r;
}
__device__ __forceinline__ float bflo(u32 u) { return __uint_as_float(u << 16); }
__device__ __forceinline__ float bfhi(u32 u) { return __uint_as_float(u & 0xffff0000u); }
// 1-instruction truncating pack: (hi16(b)<<16)|hi16(a)  [v_perm_b32]
__device__ __forceinline__ u32 pkt(float a, float b) {
  return __builtin_amdgcn_perm(__float_as_uint(b), __float_as_uint(a), 0x07060302u);
}
__device__ __forceinline__ u16 bft(float v) { return (u16)(__float_as_uint(v) >> 16); }  // trunc

// ---------------------------------------------------------------------------
// K0: swizzle ALL weights into MFMA-B fragment order (bf16, RNE).
//  B-frag layout: buf[((ntile*KS + ks)*64 + lane)*8 + j]
//  with o = ntile*16 + (lane&15), k = ks*32 + (lane>>4)*8 + j.
// ---------------------------------------------------------------------------
__global__ __launch_bounds__(256) void k_init(const float* __restrict__ w_dc,
                                              const float* __restrict__ w1,
                                              const float* __restrict__ w_ds,
                                              const float* __restrict__ w3,
                                              const float* __restrict__ w_off,
                                              u16* __restrict__ wTb, u16* __restrict__ wB1,
                                              u16* __restrict__ w3b, u16* __restrict__ woffb) {
  int idx = blockIdx.x * 256 + threadIdx.x;
  if (idx < 147456) {
    int ntile = idx / 18432, r = idx % 18432;
    int ks = r / 512, r2 = r % 512;
    int lane = r2 / 8, j = r2 % 8;
    int o = ntile * 16 + (lane & 15);
    int k = ks * 32 + ((lane >> 4) * 8) + j;
    int tap = k >> 7, ci = k & 127;
    wTb[idx] = f2bf(w_dc[(o * 128 + ci) * 9 + tap]);
  }
  int i1 = idx - 147456;
  if (i1 >= 0 && i1 < 65536) {
    int ntile = i1 / 4096, r = i1 % 4096;
    int ks = r / 512, r2 = r % 512;
    int lane = r2 / 8, j = r2 % 8;
    int o = ntile * 16 + (lane & 15);
    int c = ks * 32 + ((lane >> 4) * 8) + j;
    float v = (ntile < 8) ? w1[o * 256 + c] : w_ds[(o - 128) * 256 + c];
    wB1[i1] = f2bf(v);
  }
  int i2 = idx - 212992;
  if (i2 >= 0 && i2 < 16384) {
    int ntile = i2 / 2048, r = i2 % 2048;
    int ks = r / 512, r2 = r % 512;
    int lane = r2 / 8, j = r2 % 8;
    int o = ntile * 16 + (lane & 15);
    int c = ks * 32 + ((lane >> 4) * 8) + j;
    w3b[i2] = f2bf(w3[o * 128 + c]);
  }
  int i3 = idx - 229376;
  if (i3 >= 0 && i3 < 36864) {
    int ntile = i3 / 18432, r = i3 % 18432;
    int ks = r / 512, r2 = r % 512;
    int lane = r2 / 8, j = r2 % 8;
    int oc = ntile * 16 + (lane & 15);
    int k = ks * 32 + ((lane >> 4) * 8) + j;
    int tap = k >> 7, c = k & 127;
    woffb[i3] = (oc < 27) ? f2bf(w_off[oc * 1152 + c * 9 + tap]) : (u16)0;
  }
}

// ---------------------------------------------------------------------------
// K1 v3: fused conv1+downsample MFMA GEMM. M=32, N=256, K=256.
//  (proven; unchanged) grid (4,128,4); block 256 = 4 waves.
// ---------------------------------------------------------------------------
__global__ __launch_bounds__(256) void k_fused1(const float* __restrict__ x,
                                                const u16* __restrict__ wB1,
                                                const float* __restrict__ s1a, const float* __restrict__ t1a,
                                                const float* __restrict__ s1b, const float* __restrict__ t1b,
                                                const float* __restrict__ b_ds,
                                                const float* __restrict__ sd, const float* __restrict__ td,
                                                u16* __restrict__ out1,      // [b][h][w][o]
                                                u16* __restrict__ identb)    // [b][o][h][w]
{
  __shared__ __align__(16) u16 xA[8704];
  const int tid = threadIdx.x;
  const int wq = blockIdx.x, h = blockIdx.y, b = blockIdx.z;
  const int wave = tid >> 6, lane = tid & 63;

  {
    const float* xb = x + (size_t)b * 256 * HW + h * 128 + wq * 32;
    u32* dst = (u32*)xA;                 // u32 pitch 133 per pos row
    int cp = tid >> 3, wg = tid & 7;
#pragma unroll
    for (int i = 0; i < 4; ++i) {
      int cpair = i * 32 + cp;           // 0..127
      int c0 = cpair * 2;
      float4 va = *(const float4*)&xb[(size_t)c0 * HW + wg * 4];
      float4 vb = *(const float4*)&xb[(size_t)(c0 + 1) * HW + wg * 4];
      int p0 = wg * 4;
      dst[(p0 + 0) * 133 + cpair] = pkt(va.x, vb.x);
      dst[(p0 + 1) * 133 + cpair] = pkt(va.y, vb.y);
      dst[(p0 + 2) * 133 + cpair] = pkt(va.z, vb.z);
      dst[(p0 + 3) * 133 + cpair] = pkt(va.w, vb.w);
    }
  }
  __syncthreads();

  const int nlo = lane & 15, kgr = lane >> 4;
  float4v acc[2][4];
#pragma unroll
  for (int mt = 0; mt < 2; ++mt)
#pragma unroll
    for (int nt = 0; nt < 4; ++nt) acc[mt][nt] = (float4v)(0.f);

  const u16* a0p = &xA[nlo * 266 + kgr * 8];
  const u16* a1p = &xA[(nlo + 16) * 266 + kgr * 8];
  const u16* bp = &wB1[(((size_t)(wave * 4) * 8) * 64 + lane) * 8];

#pragma unroll
  for (int ks = 0; ks < 8; ++ks) {
    short8v a0 = *(const short8v*)(a0p + ks * 32);
    short8v a1 = *(const short8v*)(a1p + ks * 32);
#pragma unroll
    for (int nt = 0; nt < 4; ++nt) {
      short8v bv = *(const short8v*)(bp + nt * 4096 + ks * 512);
      acc[0][nt] = __builtin_amdgcn_mfma_f32_16x16x32_bf16(a0, bv, acc[0][nt], 0, 0, 0);
      acc[1][nt] = __builtin_amdgcn_mfma_f32_16x16x32_bf16(a1, bv, acc[1][nt], 0, 0, 0);
    }
  }
  __syncthreads();   // xA dead; reuse as P1 + T1

  u16* P1 = xA;              // [pos][136]
  u16* T1 = xA + 4352;       // [o][34]

  const int rbase = kgr * 4;
  if (wave < 2) {
#pragma unroll
    for (int nt = 0; nt < 4; ++nt) {
      int o = (wave * 4 + nt) * 16 + nlo;
      float sa = s1a[o], ta = t1a[o], sb = s1b[o], tb = t1b[o];
#pragma unroll
      for (int mt = 0; mt < 2; ++mt)
#pragma unroll
        for (int r = 0; r < 4; ++r) {
          float v = acc[mt][nt][r];
          v = fmaxf(sa * v + ta, 0.f);
          v = fmaxf(sb * v + tb, 0.f);
          int pos = mt * 16 + rbase + r;
          P1[pos * 136 + o] = bft(v);
        }
    }
  } else {
#pragma unroll
    for (int nt = 0; nt < 4; ++nt) {
      int og = (wave * 4 + nt) * 16 + nlo - 128;
      float sv = sd[og], tv = td[og], bv = b_ds[og];
#pragma unroll
      for (int mt = 0; mt < 2; ++mt)
#pragma unroll
        for (int r = 0; r < 4; ++r) {
          float v = sv * (acc[mt][nt][r] + bv) + tv;
          T1[og * 34 + mt * 16 + rbase + r] = bft(v);
        }
    }
  }
  __syncthreads();

  // ---- out1: fully-coalesced uint4 stores ----
  {
    size_t rowbase = ((size_t)((b * 128 + h) * 128 + wq * 32)) * 128;
#pragma unroll
    for (int i = 0; i < 2; ++i) {
      int s = i * 256 + tid;             // 0..511
      int pos = s >> 4, q = s & 15;
      uint4 v = *(const uint4*)&P1[pos * 136 + q * 8];
      *(uint4*)&out1[rowbase + (size_t)pos * 128 + q * 8] = v;
    }
  }
  // ---- identb: transpose store ----
  {
    int o = tid >> 1, half = tid & 1;
    const u16* src = &T1[o * 34 + half * 16];
    u32 bb[8];
#pragma unroll
    for (int i = 0; i < 8; ++i) bb[i] = *(const u32*)(src + i * 2);
    size_t g = ((size_t)((b * 128 + o) * 128 + h)) * 128 + wq * 32 + half * 16;
    *(uint4*)&identb[g] = make_uint4(bb[0], bb[1], bb[2], bb[3]);
    *(uint4*)&identb[g + 8] = make_uint4(bb[4], bb[5], bb[6], bb[7]);
  }
}

// ---------------------------------------------------------------------------
// K2: MEGA-FUSED DCNv2, v10 = v9 with corner gathers moved to the LDS pipe.
//  W widened to the full corner window: 5 rows (h-2..h+2) x 36 cols
//  (w0-2..w0+33), pitch 136 u16 -> 48,960 B, staged once in A1.
//  jobtab stays BYTE-IDENTICAL to proven v9 (global element offsets);
//  loop B DECODES each offset (yc=co>>14, xc=(co>>7)&127), tests the window
//  bound, and reads the corner from W via ds_read_b128 (TA-pipe -> LDS-pipe);
//  rare out-of-window corners take the proven global path.
//  W / Jl / offp fully DISJOINT (no v5-style overlay). Reduce/conv3/epilogue
//  byte-identical to v9 (reuse dead-W region [0,26112)).
//  LDS 66,368 B -> 2 blocks/CU (occupancy sacrificed deliberately; evidence
//  R1 vs R10 shows time is occupancy-insensitive).
//  grid (4,128,4); block 512. XCD swizzle + setprio kept.
// ---------------------------------------------------------------------------
__global__ __launch_bounds__(512) void k_dcn(const u16* __restrict__ out1,
                                             const u16* __restrict__ wTb,
                                             const u16* __restrict__ w3b,
                                             const u16* __restrict__ woffb,
                                             const float* __restrict__ b_off,
                                             const float* __restrict__ b_dc,
                                             const float* __restrict__ s2, const float* __restrict__ t2,
                                             const float* __restrict__ s3a, const float* __restrict__ t3a,
                                             const float* __restrict__ s3b, const float* __restrict__ t3b,
                                             const u16* __restrict__ identb,
                                             float* __restrict__ out) {
  // Layout (66,368 B total):
  //  W    [0, 48960)      : 180 px x 136 u16 (5x36 window) — live A1..loopB
  //  Jl   [48960, 58176)  : 288 jobs x 8 u32 — live A3..loopB
  //  offp [58176, 66368)  : 2x32x32 f32 — live A2..A3
  //  reduce phase (W dead): P [0,8704) 32x136 u16 ; Pp [9216,25600) 4096 f32
  //  conv3/epilogue       : P + T2 [9216,26112) 128x33 f32 (Pp dead)
  __shared__ __align__(16) u16 U[33184];

  u16*   W    = U;                                  // pitch 136 u16
  u32*   Jl   = (u32*)((char*)U + 48960);           // jobtab
  float* offp = (float*)((char*)U + 58176);         // [kg2][pos32][oc32]
  float* Pp   = (float*)((char*)U + 9216);          // [mh][ks][r4][o128]
  u16*   P    = U;                                  // [pos32][136]
  float* T2   = (float*)((char*)U + 9216);          // [o][33]

  const int tid = threadIdx.x;
  // XCD-chunked bijective swizzle (2048 blocks, 8 XCDs, 2048%8==0)
  const int flat = blockIdx.x + (blockIdx.y << 2) + (blockIdx.z << 9);
  const int nid = (flat & 7) * 256 + (flat >> 3);
  const int wq = nid & 3, h = (nid >> 2) & 127, b = nid >> 9;
  const int wave = tid >> 6, lane = tid & 63;
  const int nlo = lane & 15, kgr = lane >> 4;
  const u16* base = out1 + (size_t)b * HW * 128;
  const int w0 = wq * 32;

  // ---- A1: stage 5x36x128 window (uint4 loads; zero OOB) ----
  for (int k = tid; k < 2880; k += 512) {           // 180 px * 16 quads
    int pix = k >> 4, q = k & 15;
    int ri = pix / 36, ci = pix % 36;
    int y = h - 2 + ri, x = w0 - 2 + ci;
    uint4 g = make_uint4(0u, 0u, 0u, 0u);
    if ((y >= 0) & (y < 128) & (x >= 0) & (x < 128))
      g = *(const uint4*)&base[((size_t)(y * 128 + x)) * 128 + q * 8];
    *(uint4*)&W[pix * 136 + q * 8] = g;
  }
  __syncthreads();

  // ---- A2: offset conv, 9 taps; 8 waves = ntile(2) x mt(2) x kg(2) ----
  // tap (ty,tx), pos p: image (h-1+ty, w0+p-1+tx) -> W entry (ty+1)*36 + p+tx+1
  {
    const int ntile = wave & 1, mt = (wave >> 1) & 1, kg = wave >> 2;
    const int t0 = kg ? 5 : 0, t1 = kg ? 9 : 5;
    float4v oacc = (float4v)(0.f);
    for (int t = t0; t < t1; ++t) {
      int ty = t / 3, tx = t % 3;
      const u16* bp = &woffb[(((size_t)(ntile * 36 + t * 4)) * 64 + lane) * 8];
      const u16* ap = &W[((ty + 1) * 36 + mt * 16 + nlo + tx + 1) * 136 + kgr * 8];
#pragma unroll
      for (int ksl = 0; ksl < 4; ++ksl) {
        short8v bv = *(const short8v*)(bp + ksl * 512);
        short8v a = *(const short8v*)(ap + ksl * 32);
        oacc = __builtin_amdgcn_mfma_f32_16x16x32_bf16(a, bv, oacc, 0, 0, 0);
      }
    }
    int oc = ntile * 16 + nlo;
#pragma unroll
    for (int r = 0; r < 4; ++r)
      offp[kg * 1024 + (mt * 16 + kgr * 4 + r) * 32 + oc] = oacc[r];
  }
  __syncthreads();

  // ---- A3: per-job clamped corner offsets + weights -> jobtab (v9-proven) ----
  if (tid < 288) {
    int pos = tid / 9, tap = tid % 9;
    int w = w0 + pos;
    float dy  = offp[pos * 32 + tap]      + offp[1024 + pos * 32 + tap]      + b_off[tap];
    float dxv = offp[pos * 32 + 9 + tap]  + offp[1024 + pos * 32 + 9 + tap]  + b_off[9 + tap];
    float sg  = offp[pos * 32 + 18 + tap] + offp[1024 + pos * 32 + 18 + tap] + b_off[18 + tap];
    float mk = 1.f / (1.f + __expf(-sg));
    float py = (float)(h - 1 + tap / 3) + dy;
    float px = (float)(w - 1 + tap % 3) + dxv;
    float fy = floorf(py), fx = floorf(px);
    int y0 = (int)fy, x0 = (int)fx;
    float wy = py - fy, wxf = px - fx;
    bool vy0 = (y0 >= 0) & (y0 < 128), vy1 = (y0 >= -1) & (y0 < 127);
    bool vx0 = (x0 >= 0) & (x0 < 128), vx1 = (x0 >= -1) & (x0 < 127);
    float w00 = (vy0 & vx0) ? (1.f - wy) * (1.f - wxf) * mk : 0.f;
    float w01 = (vy0 & vx1) ? (1.f - wy) * wxf * mk : 0.f;
    float w10 = (vy1 & vx0) ? wy * (1.f - wxf) * mk : 0.f;
    float w11 = (vy1 & vx1) ? wy * wxf * mk : 0.f;
    int y0c = min(max(y0, 0), 127), y1c = min(max(y0 + 1, 0), 127);
    int x0c = min(max(x0, 0), 127), x1c = min(max(x0 + 1, 0), 127);
    u32* jt = &Jl[tid * 8];
    jt[0] = (u32)((y0c * 128 + x0c) * 128);
    jt[1] = (u32)((y0c * 128 + x1c) * 128);
    jt[2] = (u32)((y1c * 128 + x0c) * 128);
    jt[3] = (u32)((y1c * 128 + x1c) * 128);
    ((float*)jt)[4] = w00; ((float*)jt)[5] = w01;
    ((float*)jt)[6] = w10; ((float*)jt)[7] = w11;
  }
  __syncthreads();

  // ---- Loop B: DCN conv, K-split, barrier-free; corners from LDS window ----
  float4v acc8[8];
#pragma unroll
  for (int nt = 0; nt < 8; ++nt) acc8[nt] = (float4v)(0.f);
  {
    const int ks = wave & 3, mh = wave >> 2;
    const int ch0 = ks * 32 + kgr * 8;      // this lane's 8-channel group
    const int jrow = (mh * 16 + nlo) * 9;   // jobs of this lane's pos

#pragma unroll
    for (int t = 0; t < 9; ++t) {
      const u32* jt = &Jl[(jrow + t) * 8];
      uint4 co4 = *(const uint4*)jt;
      float4 w4 = *(const float4*)(jt + 4);
      u32 cos[4] = {co4.x, co4.y, co4.z, co4.w};
      float wf[4] = {w4.x, w4.y, w4.z, w4.w};
      float alo[4] = {0.f, 0.f, 0.f, 0.f};
      float ahi[4] = {0.f, 0.f, 0.f, 0.f};
#pragma unroll
      for (int c = 0; c < 4; ++c) {
        u32 co = cos[c];
        int yc = (int)(co >> 14), xc = (int)((co >> 7) & 127);
        int ri = yc - h + 2, ci = xc - w0 + 2;
        short8v cv;
        if (((unsigned)ri < 5u) && ((unsigned)ci < 36u))
          cv = *(const short8v*)&W[(ri * 36 + ci) * 136 + ch0];   // LDS pipe
        else
          cv = *(const short8v*)(base + co + ch0);                // rare global
        union { short8v s; u32 u[4]; } cc; cc.s = cv;
        float wk = wf[c];
#pragma unroll
        for (int p = 0; p < 4; ++p) {
          alo[p] = fmaf(wk, bflo(cc.u[p]), alo[p]);
          ahi[p] = fmaf(wk, bfhi(cc.u[p]), ahi[p]);
        }
      }
      union { u32 u[4]; short8v s; } av;
#pragma unroll
      for (int p = 0; p < 4; ++p) av.u[p] = pkt(alo[p], ahi[p]);
      {
        const u16* bb = &wTb[(((size_t)(t * 4 + ks)) * 64 + lane) * 8];
        __builtin_amdgcn_s_setprio(1);
#pragma unroll
        for (int nt = 0; nt < 8; ++nt) {
          short8v bv = *(const short8v*)(bb + (size_t)nt * 18432);
          acc8[nt] = __builtin_amdgcn_mfma_f32_16x16x32_bf16(av.s, bv, acc8[nt], 0, 0, 0);
        }
        __builtin_amdgcn_s_setprio(0);
      }
    }
  }
  __syncthreads();   // W + jobtab dead; U[0,26112) reusable

  // ---- Reduction: 4 stages x 4 pos; combine 4 K-partials + bn2 -> P ----
  {
    const int ks = wave & 3, mh = wave >> 2;
#pragma unroll
    for (int s = 0; s < 4; ++s) {
      if (kgr == s) {
#pragma unroll
        for (int nt = 0; nt < 8; ++nt)
#pragma unroll
          for (int r = 0; r < 4; ++r)
            Pp[mh * 2048 + ks * 512 + r * 128 + nt * 16 + nlo] = acc8[nt][r];
      }
      __syncthreads();
#pragma unroll
      for (int q = 0; q < 2; ++q) {
        int idx = q * 512 + tid;
        int mi = idx >> 9, rem = idx & 511;
        int p = rem >> 7, o = rem & 127;
        const float* Pb = Pp + mi * 2048 + p * 128 + o;
        float sv = Pb[0] + Pb[512] + Pb[1024] + Pb[1536];
        float v = sv + b_dc[o];
        v = fmaxf(s2[o] * v + t2[o], 0.f);
        P[(mi * 16 + s * 4 + p) * 136 + o] = bft(v);
      }
      __syncthreads();
    }
  }

  // ---- conv3 MFMA (M=32, K=128): wave owns o-tile = wave, both m-tiles ----
  float4v acc2[2];
  acc2[0] = (float4v)(0.f); acc2[1] = (float4v)(0.f);
  {
    const u16* bp3 = &w3b[(((size_t)(wave * 4)) * 64 + lane) * 8];
#pragma unroll
    for (int ks3 = 0; ks3 < 4; ++ks3) {
      short8v bv = *(const short8v*)(bp3 + ks3 * 512);
#pragma unroll
      for (int mt = 0; mt < 2; ++mt) {
        short8v a = *(const short8v*)&P[(mt * 16 + nlo) * 136 + ks3 * 32 + kgr * 8];
        acc2[mt] = __builtin_amdgcn_mfma_f32_16x16x32_bf16(a, bv, acc2[mt], 0, 0, 0);
      }
    }
  }

  // bn3 chain -> T2[o][pos33] (overlays dead Pp; P region disjoint)
  {
    int o = wave * 16 + nlo;
    float sa = s3a[o], ta = t3a[o], sb = s3b[o], tb = t3b[o];
#pragma unroll
    for (int mt = 0; mt < 2; ++mt)
#pragma unroll
      for (int r = 0; r < 4; ++r) {
        float v = acc2[mt][r];
        v = fmaxf(sa * v + ta, 0.f);
        v = sb * v + tb;
        T2[o * 33 + mt * 16 + kgr * 4 + r] = v;
      }
  }
  __syncthreads();

  // ---- transpose + ident + relu -> out NCHW fp32 ----
  {
    int o = tid >> 2, qd = tid & 3;
    size_t g = ((size_t)((b * 128 + o) * 128 + h)) * 128 + w0 + qd * 8;
    const float* trow = &T2[o * 33 + qd * 8];
    uint4 iv = *(const uint4*)&identb[g];
    u32 iw[4] = {iv.x, iv.y, iv.z, iv.w};
    float4 ov[2];
#pragma unroll
    for (int q = 0; q < 2; ++q) {
      float r0 = trow[q * 4 + 0] + bflo(iw[q * 2]);
      float r1 = trow[q * 4 + 1] + bfhi(iw[q * 2]);
      float r2 = trow[q * 4 + 2] + bflo(iw[q * 2 + 1]);
      float r3 = trow[q * 4 + 3] + bfhi(iw[q * 2 + 1]);
      ov[q] = make_float4(fmaxf(r0, 0.f), fmaxf(r1, 0.f), fmaxf(r2, 0.f), fmaxf(r3, 0.f));
    }
    *(float4*)&out[g] = ov[0];
    *(float4*)&out[g + 4] = ov[1];
  }
}

// ---------------------------------------------------------------------------
extern "C" void kernel_launch(void* const* d_in, const int* in_sizes, int n_in,
                              void* d_out, int out_size, void* d_ws, size_t ws_size,
                              hipStream_t stream) {
  const float* x     = (const float*)d_in[0];
  const float* w1    = (const float*)d_in[1];
  const float* s1a   = (const float*)d_in[2];
  const float* t1a   = (const float*)d_in[3];
  const float* s1b   = (const float*)d_in[4];
  const float* t1b   = (const float*)d_in[5];
  const float* w_off = (const float*)d_in[6];
  const float* b_off = (const float*)d_in[7];
  const float* w_dc  = (const float*)d_in[8];
  const float* b_dc  = (const float*)d_in[9];
  const float* s2    = (const float*)d_in[10];
  const float* t2    = (const float*)d_in[11];
  const float* w3    = (const float*)d_in[12];
  const float* s3a   = (const float*)d_in[13];
  const float* t3a   = (const float*)d_in[14];
  const float* s3b   = (const float*)d_in[15];
  const float* t3b   = (const float*)d_in[16];
  const float* w_ds  = (const float*)d_in[17];
  const float* b_ds  = (const float*)d_in[18];
  const float* sd    = (const float*)d_in[19];
  const float* td    = (const float*)d_in[20];

  char* ws = (char*)d_ws;
  u16* wTb    = (u16*)(ws + 0);            //    294,912 B
  u16* wB1    = (u16*)(ws + 294912);       //    131,072 B
  u16* w3b    = (u16*)(ws + 425984);       //     32,768 B
  u16* woffb  = (u16*)(ws + 458752);       //     73,728 B
  u16* out1   = (u16*)(ws + 532480);       // 16,777,216 B  NHWC bf16
  u16* identb = (u16*)(ws + 17309696);     // 16,777,216 B  NCHW bf16

  k_init  <<<1040, 256, 0, stream>>>(w_dc, w1, w_ds, w3, w_off, wTb, wB1, w3b, woffb);
  k_fused1<<<dim3(4, 128, 4), 256, 0, stream>>>(x, wB1, s1a, t1a, s1b, t1b, b_ds, sd, td, out1, identb);
  k_dcn   <<<dim3(4, 128, 4), 512, 0, stream>>>(out1, wTb, w3b, woffb, b_off, b_dc, s2, t2,
                                                s3a, t3a, s3b, t3b, identb, (float*)d_out);
}

// Round 12
// 240.970 us; speedup vs baseline: 1.2055x; 1.0148x over previous
//
#include <hip/hip_runtime.h>
#include <hip/hip_bf16.h>

#define HW 16384   // 128*128

typedef unsigned short u16;
typedef unsigned int   u32;
typedef __attribute__((ext_vector_type(8))) short short8v;
typedef __attribute__((ext_vector_type(4))) float float4v;

__device__ __forceinline__ float b2f(u16 v) { return __uint_as_float((u32)v << 16); }
__device__ __forceinline__ u16 f2bf(float f) {   // RNE (cold paths)
  u32 u = __float_as_uint(f);
  u32 r = (u + 0x7fffu + ((u >> 16) & 1u)) >> 16;
  return (u16)r;
}
__device__ __forceinline__ float bflo(u32 u) { return __uint_as_float(u << 16); }
__device__ __forceinline__ float bfhi(u32 u) { return __uint_as_float(u & 0xffff0000u); }
// 1-instruction truncating pack: (hi16(b)<<16)|hi16(a)  [v_perm_b32]
__device__ __forceinline__ u32 pkt(float a, float b) {
  return __builtin_amdgcn_perm(__float_as_uint(b), __float_as_uint(a), 0x07060302u);
}
__device__ __forceinline__ u16 bft(float v) { return (u16)(__float_as_uint(v) >> 16); }  // trunc

// ---------------------------------------------------------------------------
// K0: swizzle ALL weights into MFMA-B fragment order (bf16, RNE).
//  B-frag layout: buf[((ntile*KS + ks)*64 + lane)*8 + j]
//  with o = ntile*16 + (lane&15), k = ks*32 + (lane>>4)*8 + j.
// ---------------------------------------------------------------------------
__global__ __launch_bounds__(256) void k_init(const float* __restrict__ w_dc,
                                              const float* __restrict__ w1,
                                              const float* __restrict__ w_ds,
                                              const float* __restrict__ w3,
                                              const float* __restrict__ w_off,
                                              u16* __restrict__ wTb, u16* __restrict__ wB1,
                                              u16* __restrict__ w3b, u16* __restrict__ woffb) {
  int idx = blockIdx.x * 256 + threadIdx.x;
  if (idx < 147456) {
    int ntile = idx / 18432, r = idx % 18432;
    int ks = r / 512, r2 = r % 512;
    int lane = r2 / 8, j = r2 % 8;
    int o = ntile * 16 + (lane & 15);
    int k = ks * 32 + ((lane >> 4) * 8) + j;
    int tap = k >> 7, ci = k & 127;
    wTb[idx] = f2bf(w_dc[(o * 128 + ci) * 9 + tap]);
  }
  int i1 = idx - 147456;
  if (i1 >= 0 && i1 < 65536) {
    int ntile = i1 / 4096, r = i1 % 4096;
    int ks = r / 512, r2 = r % 512;
    int lane = r2 / 8, j = r2 % 8;
    int o = ntile * 16 + (lane & 15);
    int c = ks * 32 + ((lane >> 4) * 8) + j;
    float v = (ntile < 8) ? w1[o * 256 + c] : w_ds[(o - 128) * 256 + c];
    wB1[i1] = f2bf(v);
  }
  int i2 = idx - 212992;
  if (i2 >= 0 && i2 < 16384) {
    int ntile = i2 / 2048, r = i2 % 2048;
    int ks = r / 512, r2 = r % 512;
    int lane = r2 / 8, j = r2 % 8;
    int o = ntile * 16 + (lane & 15);
    int c = ks * 32 + ((lane >> 4) * 8) + j;
    w3b[i2] = f2bf(w3[o * 128 + c]);
  }
  int i3 = idx - 229376;
  if (i3 >= 0 && i3 < 36864) {
    int ntile = i3 / 18432, r = i3 % 18432;
    int ks = r / 512, r2 = r % 512;
    int lane = r2 / 8, j = r2 % 8;
    int oc = ntile * 16 + (lane & 15);
    int k = ks * 32 + ((lane >> 4) * 8) + j;
    int tap = k >> 7, c = k & 127;
    woffb[i3] = (oc < 27) ? f2bf(w_off[oc * 1152 + c * 9 + tap]) : (u16)0;
  }
}

// ---------------------------------------------------------------------------
// K1 v3: fused conv1+downsample MFMA GEMM. M=32, N=256, K=256.
//  (proven; unchanged) grid (4,128,4); block 256 = 4 waves.
// ---------------------------------------------------------------------------
__global__ __launch_bounds__(256) void k_fused1(const float* __restrict__ x,
                                                const u16* __restrict__ wB1,
                                                const float* __restrict__ s1a, const float* __restrict__ t1a,
                                                const float* __restrict__ s1b, const float* __restrict__ t1b,
                                                const float* __restrict__ b_ds,
                                                const float* __restrict__ sd, const float* __restrict__ td,
                                                u16* __restrict__ out1,      // [b][h][w][o]
                                                u16* __restrict__ identb)    // [b][o][h][w]
{
  __shared__ __align__(16) u16 xA[8704];
  const int tid = threadIdx.x;
  const int wq = blockIdx.x, h = blockIdx.y, b = blockIdx.z;
  const int wave = tid >> 6, lane = tid & 63;

  {
    const float* xb = x + (size_t)b * 256 * HW + h * 128 + wq * 32;
    u32* dst = (u32*)xA;                 // u32 pitch 133 per pos row
    int cp = tid >> 3, wg = tid & 7;
#pragma unroll
    for (int i = 0; i < 4; ++i) {
      int cpair = i * 32 + cp;           // 0..127
      int c0 = cpair * 2;
      float4 va = *(const float4*)&xb[(size_t)c0 * HW + wg * 4];
      float4 vb = *(const float4*)&xb[(size_t)(c0 + 1) * HW + wg * 4];
      int p0 = wg * 4;
      dst[(p0 + 0) * 133 + cpair] = pkt(va.x, vb.x);
      dst[(p0 + 1) * 133 + cpair] = pkt(va.y, vb.y);
      dst[(p0 + 2) * 133 + cpair] = pkt(va.z, vb.z);
      dst[(p0 + 3) * 133 + cpair] = pkt(va.w, vb.w);
    }
  }
  __syncthreads();

  const int nlo = lane & 15, kgr = lane >> 4;
  float4v acc[2][4];
#pragma unroll
  for (int mt = 0; mt < 2; ++mt)
#pragma unroll
    for (int nt = 0; nt < 4; ++nt) acc[mt][nt] = (float4v)(0.f);

  const u16* a0p = &xA[nlo * 266 + kgr * 8];
  const u16* a1p = &xA[(nlo + 16) * 266 + kgr * 8];
  const u16* bp = &wB1[(((size_t)(wave * 4) * 8) * 64 + lane) * 8];

#pragma unroll
  for (int ks = 0; ks < 8; ++ks) {
    short8v a0 = *(const short8v*)(a0p + ks * 32);
    short8v a1 = *(const short8v*)(a1p + ks * 32);
#pragma unroll
    for (int nt = 0; nt < 4; ++nt) {
      short8v bv = *(const short8v*)(bp + nt * 4096 + ks * 512);
      acc[0][nt] = __builtin_amdgcn_mfma_f32_16x16x32_bf16(a0, bv, acc[0][nt], 0, 0, 0);
      acc[1][nt] = __builtin_amdgcn_mfma_f32_16x16x32_bf16(a1, bv, acc[1][nt], 0, 0, 0);
    }
  }
  __syncthreads();   // xA dead; reuse as P1 + T1

  u16* P1 = xA;              // [pos][136]
  u16* T1 = xA + 4352;       // [o][34]

  const int rbase = kgr * 4;
  if (wave < 2) {
#pragma unroll
    for (int nt = 0; nt < 4; ++nt) {
      int o = (wave * 4 + nt) * 16 + nlo;
      float sa = s1a[o], ta = t1a[o], sb = s1b[o], tb = t1b[o];
#pragma unroll
      for (int mt = 0; mt < 2; ++mt)
#pragma unroll
        for (int r = 0; r < 4; ++r) {
          float v = acc[mt][nt][r];
          v = fmaxf(sa * v + ta, 0.f);
          v = fmaxf(sb * v + tb, 0.f);
          int pos = mt * 16 + rbase + r;
          P1[pos * 136 + o] = bft(v);
        }
    }
  } else {
#pragma unroll
    for (int nt = 0; nt < 4; ++nt) {
      int og = (wave * 4 + nt) * 16 + nlo - 128;
      float sv = sd[og], tv = td[og], bv = b_ds[og];
#pragma unroll
      for (int mt = 0; mt < 2; ++mt)
#pragma unroll
        for (int r = 0; r < 4; ++r) {
          float v = sv * (acc[mt][nt][r] + bv) + tv;
          T1[og * 34 + mt * 16 + rbase + r] = bft(v);
        }
    }
  }
  __syncthreads();

  // ---- out1: fully-coalesced uint4 stores ----
  {
    size_t rowbase = ((size_t)((b * 128 + h) * 128 + wq * 32)) * 128;
#pragma unroll
    for (int i = 0; i < 2; ++i) {
      int s = i * 256 + tid;             // 0..511
      int pos = s >> 4, q = s & 15;
      uint4 v = *(const uint4*)&P1[pos * 136 + q * 8];
      *(uint4*)&out1[rowbase + (size_t)pos * 128 + q * 8] = v;
    }
  }
  // ---- identb: transpose store ----
  {
    int o = tid >> 1, half = tid & 1;
    const u16* src = &T1[o * 34 + half * 16];
    u32 bb[8];
#pragma unroll
    for (int i = 0; i < 8; ++i) bb[i] = *(const u32*)(src + i * 2);
    size_t g = ((size_t)((b * 128 + o) * 128 + h)) * 128 + wq * 32 + half * 16;
    *(uint4*)&identb[g] = make_uint4(bb[0], bb[1], bb[2], bb[3]);
    *(uint4*)&identb[g + 8] = make_uint4(bb[4], bb[5], bb[6], bb[7]);
  }
}

// ---------------------------------------------------------------------------
// K2: MEGA-FUSED DCNv2, v11 = v10 (PROVEN, 102 us) + two VALU/barrier cuts:
//  (1) corner-window DECODE HOISTED to A3: jobtab stores
//      code = in_window ? (0x80000000 | W_u16_index) : global_elem_offset.
//      Decode ran 4x-duplicated (per kgr replica) inside loop B; now once
//      per job. The predicate/index expressions are IDENTICAL to v10's
//      proven in-loop decode, just moved. Global offsets < 2^21 so bit31
//      is an unambiguous tag.
//  (2) reduction reverted to v8's proven 2-stage form (4 barriers, Pp 32 KB
//      fits in dead-W region; LDS block size unchanged at 66.4 KB).
//  Everything else byte-identical to v10 (window staging, A2, loop B MFMA,
//  XCD swizzle, setprio, conv3, epilogue).
//  grid (4,128,4); block 512. LDS 66,368 B -> 2 blocks/CU.
// ---------------------------------------------------------------------------
__global__ __launch_bounds__(512) void k_dcn(const u16* __restrict__ out1,
                                             const u16* __restrict__ wTb,
                                             const u16* __restrict__ w3b,
                                             const u16* __restrict__ woffb,
                                             const float* __restrict__ b_off,
                                             const float* __restrict__ b_dc,
                                             const float* __restrict__ s2, const float* __restrict__ t2,
                                             const float* __restrict__ s3a, const float* __restrict__ t3a,
                                             const float* __restrict__ s3b, const float* __restrict__ t3b,
                                             const u16* __restrict__ identb,
                                             float* __restrict__ out) {
  // Layout (66,368 B total):
  //  W    [0, 48960)      : 180 px x 136 u16 (5x36 window) — live A1..loopB
  //  Jl   [48960, 58176)  : 288 jobs x 8 u32 — live A3..loopB
  //  offp [58176, 66368)  : 2x32x32 f32 — live A2..A3
  //  reduce phase (W dead): P [0,8704) 32x136 u16 ; Pp [9216,41984) 8192 f32
  //  conv3/epilogue       : P + T2 [9216,26112) 128x33 f32 (Pp dead)
  __shared__ __align__(16) u16 U[33184];

  u16*   W    = U;                                  // pitch 136 u16
  u32*   Jl   = (u32*)((char*)U + 48960);           // jobtab
  float* offp = (float*)((char*)U + 58176);         // [kg2][pos32][oc32]
  float* Pp   = (float*)((char*)U + 9216);          // [mh][ks][p8][o128]
  u16*   P    = U;                                  // [pos32][136]
  float* T2   = (float*)((char*)U + 9216);          // [o][33]

  const int tid = threadIdx.x;
  // XCD-chunked bijective swizzle (2048 blocks, 8 XCDs, 2048%8==0)
  const int flat = blockIdx.x + (blockIdx.y << 2) + (blockIdx.z << 9);
  const int nid = (flat & 7) * 256 + (flat >> 3);
  const int wq = nid & 3, h = (nid >> 2) & 127, b = nid >> 9;
  const int wave = tid >> 6, lane = tid & 63;
  const int nlo = lane & 15, kgr = lane >> 4;
  const u16* base = out1 + (size_t)b * HW * 128;
  const int w0 = wq * 32;

  // ---- A1: stage 5x36x128 window (uint4 loads; zero OOB) ----
  for (int k = tid; k < 2880; k += 512) {           // 180 px * 16 quads
    int pix = k >> 4, q = k & 15;
    int ri = pix / 36, ci = pix % 36;
    int y = h - 2 + ri, x = w0 - 2 + ci;
    uint4 g = make_uint4(0u, 0u, 0u, 0u);
    if ((y >= 0) & (y < 128) & (x >= 0) & (x < 128))
      g = *(const uint4*)&base[((size_t)(y * 128 + x)) * 128 + q * 8];
    *(uint4*)&W[pix * 136 + q * 8] = g;
  }
  __syncthreads();

  // ---- A2: offset conv, 9 taps; 8 waves = ntile(2) x mt(2) x kg(2) ----
  {
    const int ntile = wave & 1, mt = (wave >> 1) & 1, kg = wave >> 2;
    const int t0 = kg ? 5 : 0, t1 = kg ? 9 : 5;
    float4v oacc = (float4v)(0.f);
    for (int t = t0; t < t1; ++t) {
      int ty = t / 3, tx = t % 3;
      const u16* bp = &woffb[(((size_t)(ntile * 36 + t * 4)) * 64 + lane) * 8];
      const u16* ap = &W[((ty + 1) * 36 + mt * 16 + nlo + tx + 1) * 136 + kgr * 8];
#pragma unroll
      for (int ksl = 0; ksl < 4; ++ksl) {
        short8v bv = *(const short8v*)(bp + ksl * 512);
        short8v a = *(const short8v*)(ap + ksl * 32);
        oacc = __builtin_amdgcn_mfma_f32_16x16x32_bf16(a, bv, oacc, 0, 0, 0);
      }
    }
    int oc = ntile * 16 + nlo;
#pragma unroll
    for (int r = 0; r < 4; ++r)
      offp[kg * 1024 + (mt * 16 + kgr * 4 + r) * 32 + oc] = oacc[r];
  }
  __syncthreads();

  // ---- A3: per-job corner CODES (decode hoisted from loop B) + weights ----
  if (tid < 288) {
    int pos = tid / 9, tap = tid % 9;
    int w = w0 + pos;
    float dy  = offp[pos * 32 + tap]      + offp[1024 + pos * 32 + tap]      + b_off[tap];
    float dxv = offp[pos * 32 + 9 + tap]  + offp[1024 + pos * 32 + 9 + tap]  + b_off[9 + tap];
    float sg  = offp[pos * 32 + 18 + tap] + offp[1024 + pos * 32 + 18 + tap] + b_off[18 + tap];
    float mk = 1.f / (1.f + __expf(-sg));
    float py = (float)(h - 1 + tap / 3) + dy;
    float px = (float)(w - 1 + tap % 3) + dxv;
    float fy = floorf(py), fx = floorf(px);
    int y0 = (int)fy, x0 = (int)fx;
    float wy = py - fy, wxf = px - fx;
    bool vy0 = (y0 >= 0) & (y0 < 128), vy1 = (y0 >= -1) & (y0 < 127);
    bool vx0 = (x0 >= 0) & (x0 < 128), vx1 = (x0 >= -1) & (x0 < 127);
    float w00 = (vy0 & vx0) ? (1.f - wy) * (1.f - wxf) * mk : 0.f;
    float w01 = (vy0 & vx1) ? (1.f - wy) * wxf * mk : 0.f;
    float w10 = (vy1 & vx0) ? wy * (1.f - wxf) * mk : 0.f;
    float w11 = (vy1 & vx1) ? wy * wxf * mk : 0.f;
    int y0c = min(max(y0, 0), 127), y1c = min(max(y0 + 1, 0), 127);
    int x0c = min(max(x0, 0), 127), x1c = min(max(x0 + 1, 0), 127);
    // encode: in-window -> bit31 | u16-index into W; else global elem offset.
    // (identical predicate/index math to v10's proven in-loop decode)
    auto enc = [&](int yc, int xc) -> u32 {
      int ri = yc - (h - 2), ci = xc - (w0 - 2);
      if (((unsigned)ri < 5u) && ((unsigned)ci < 36u))
        return 0x80000000u | (u32)((ri * 36 + ci) * 136);
      return (u32)((yc * 128 + xc) * 128);
    };
    u32* jt = &Jl[tid * 8];
    jt[0] = enc(y0c, x0c);
    jt[1] = enc(y0c, x1c);
    jt[2] = enc(y1c, x0c);
    jt[3] = enc(y1c, x1c);
    ((float*)jt)[4] = w00; ((float*)jt)[5] = w01;
    ((float*)jt)[6] = w10; ((float*)jt)[7] = w11;
  }
  __syncthreads();

  // ---- Loop B: DCN conv, K-split, barrier-free; tagged corner reads ----
  float4v acc8[8];
#pragma unroll
  for (int nt = 0; nt < 8; ++nt) acc8[nt] = (float4v)(0.f);
  {
    const int ks = wave & 3, mh = wave >> 2;
    const int ch0 = ks * 32 + kgr * 8;      // this lane's 8-channel group
    const int jrow = (mh * 16 + nlo) * 9;   // jobs of this lane's pos

#pragma unroll
    for (int t = 0; t < 9; ++t) {
      const u32* jt = &Jl[(jrow + t) * 8];
      uint4 co4 = *(const uint4*)jt;
      float4 w4 = *(const float4*)(jt + 4);
      u32 cos[4] = {co4.x, co4.y, co4.z, co4.w};
      float wf[4] = {w4.x, w4.y, w4.z, w4.w};
      float alo[4] = {0.f, 0.f, 0.f, 0.f};
      float ahi[4] = {0.f, 0.f, 0.f, 0.f};
#pragma unroll
      for (int c = 0; c < 4; ++c) {
        u32 co = cos[c];
        short8v cv;
        if (co & 0x80000000u)
          cv = *(const short8v*)&W[(co & 0x7fffffffu) + ch0];   // LDS pipe
        else
          cv = *(const short8v*)(base + co + ch0);              // rare global
        union { short8v s; u32 u[4]; } cc; cc.s = cv;
        float wk = wf[c];
#pragma unroll
        for (int p = 0; p < 4; ++p) {
          alo[p] = fmaf(wk, bflo(cc.u[p]), alo[p]);
          ahi[p] = fmaf(wk, bfhi(cc.u[p]), ahi[p]);
        }
      }
      union { u32 u[4]; short8v s; } av;
#pragma unroll
      for (int p = 0; p < 4; ++p) av.u[p] = pkt(alo[p], ahi[p]);
      {
        const u16* bb = &wTb[(((size_t)(t * 4 + ks)) * 64 + lane) * 8];
        __builtin_amdgcn_s_setprio(1);
#pragma unroll
        for (int nt = 0; nt < 8; ++nt) {
          short8v bv = *(const short8v*)(bb + (size_t)nt * 18432);
          acc8[nt] = __builtin_amdgcn_mfma_f32_16x16x32_bf16(av.s, bv, acc8[nt], 0, 0, 0);
        }
        __builtin_amdgcn_s_setprio(0);
      }
    }
  }
  __syncthreads();   // W + jobtab dead; U[0,41984) reusable

  // ---- Reduction (v8-proven 2-stage): combine 4 K-partials + bn2 -> P ----
  {
    const int ks = wave & 3, mh = wave >> 2;
    // stage A: local pos 0..7 (kgr 0,1)
    if (kgr < 2) {
#pragma unroll
      for (int nt = 0; nt < 8; ++nt)
#pragma unroll
        for (int r = 0; r < 4; ++r)
          Pp[mh * 4096 + ks * 1024 + (kgr * 4 + r) * 128 + nt * 16 + nlo] = acc8[nt][r];
    }
    __syncthreads();
#pragma unroll
    for (int q = 0; q < 4; ++q) {
      int idx = q * 512 + tid;
      int mi = idx >> 10, rem = idx & 1023;
      int p8 = rem >> 7, o = rem & 127;
      const float* Pb = Pp + mi * 4096 + p8 * 128 + o;
      float s = Pb[0] + Pb[1024] + Pb[2048] + Pb[3072];
      float v = s + b_dc[o];
      v = fmaxf(s2[o] * v + t2[o], 0.f);
      P[(mi * 16 + p8) * 136 + o] = bft(v);
    }
    __syncthreads();
    // stage B: local pos 8..15 (kgr 2,3)
    if (kgr >= 2) {
#pragma unroll
      for (int nt = 0; nt < 8; ++nt)
#pragma unroll
        for (int r = 0; r < 4; ++r)
          Pp[mh * 4096 + ks * 1024 + ((kgr - 2) * 4 + r) * 128 + nt * 16 + nlo] = acc8[nt][r];
    }
    __syncthreads();
#pragma unroll
    for (int q = 0; q < 4; ++q) {
      int idx = q * 512 + tid;
      int mi = idx >> 10, rem = idx & 1023;
      int p8 = rem >> 7, o = rem & 127;
      const float* Pb = Pp + mi * 4096 + p8 * 128 + o;
      float s = Pb[0] + Pb[1024] + Pb[2048] + Pb[3072];
      float v = s + b_dc[o];
      v = fmaxf(s2[o] * v + t2[o], 0.f);
      P[(mi * 16 + 8 + p8) * 136 + o] = bft(v);
    }
    __syncthreads();
  }

  // ---- conv3 MFMA (M=32, K=128): wave owns o-tile = wave, both m-tiles ----
  float4v acc2[2];
  acc2[0] = (float4v)(0.f); acc2[1] = (float4v)(0.f);
  {
    const u16* bp3 = &w3b[(((size_t)(wave * 4)) * 64 + lane) * 8];
#pragma unroll
    for (int ks3 = 0; ks3 < 4; ++ks3) {
      short8v bv = *(const short8v*)(bp3 + ks3 * 512);
#pragma unroll
      for (int mt = 0; mt < 2; ++mt) {
        short8v a = *(const short8v*)&P[(mt * 16 + nlo) * 136 + ks3 * 32 + kgr * 8];
        acc2[mt] = __builtin_amdgcn_mfma_f32_16x16x32_bf16(a, bv, acc2[mt], 0, 0, 0);
      }
    }
  }

  // bn3 chain -> T2[o][pos33] (overlays dead Pp; P region disjoint)
  {
    int o = wave * 16 + nlo;
    float sa = s3a[o], ta = t3a[o], sb = s3b[o], tb = t3b[o];
#pragma unroll
    for (int mt = 0; mt < 2; ++mt)
#pragma unroll
      for (int r = 0; r < 4; ++r) {
        float v = acc2[mt][r];
        v = fmaxf(sa * v + ta, 0.f);
        v = sb * v + tb;
        T2[o * 33 + mt * 16 + kgr * 4 + r] = v;
      }
  }
  __syncthreads();

  // ---- transpose + ident + relu -> out NCHW fp32 ----
  {
    int o = tid >> 2, qd = tid & 3;
    size_t g = ((size_t)((b * 128 + o) * 128 + h)) * 128 + w0 + qd * 8;
    const float* trow = &T2[o * 33 + qd * 8];
    uint4 iv = *(const uint4*)&identb[g];
    u32 iw[4] = {iv.x, iv.y, iv.z, iv.w};
    float4 ov[2];
#pragma unroll
    for (int q = 0; q < 2; ++q) {
      float r0 = trow[q * 4 + 0] + bflo(iw[q * 2]);
      float r1 = trow[q * 4 + 1] + bfhi(iw[q * 2]);
      float r2 = trow[q * 4 + 2] + bflo(iw[q * 2 + 1]);
      float r3 = trow[q * 4 + 3] + bfhi(iw[q * 2 + 1]);
      ov[q] = make_float4(fmaxf(r0, 0.f), fmaxf(r1, 0.f), fmaxf(r2, 0.f), fmaxf(r3, 0.f));
    }
    *(float4*)&out[g] = ov[0];
    *(float4*)&out[g + 4] = ov[1];
  }
}

// ---------------------------------------------------------------------------
extern "C" void kernel_launch(void* const* d_in, const int* in_sizes, int n_in,
                              void* d_out, int out_size, void* d_ws, size_t ws_size,
                              hipStream_t stream) {
  const float* x     = (const float*)d_in[0];
  const float* w1    = (const float*)d_in[1];
  const float* s1a   = (const float*)d_in[2];
  const float* t1a   = (const float*)d_in[3];
  const float* s1b   = (const float*)d_in[4];
  const float* t1b   = (const float*)d_in[5];
  const float* w_off = (const float*)d_in[6];
  const float* b_off = (const float*)d_in[7];
  const float* w_dc  = (const float*)d_in[8];
  const float* b_dc  = (const float*)d_in[9];
  const float* s2    = (const float*)d_in[10];
  const float* t2    = (const float*)d_in[11];
  const float* w3    = (const float*)d_in[12];
  const float* s3a   = (const float*)d_in[13];
  const float* t3a   = (const float*)d_in[14];
  const float* s3b   = (const float*)d_in[15];
  const float* t3b   = (const float*)d_in[16];
  const float* w_ds  = (const float*)d_in[17];
  const float* b_ds  = (const float*)d_in[18];
  const float* sd    = (const float*)d_in[19];
  const float* td    = (const float*)d_in[20];

  char* ws = (char*)d_ws;
  u16* wTb    = (u16*)(ws + 0);            //    294,912 B
  u16* wB1    = (u16*)(ws + 294912);       //    131,072 B
  u16* w3b    = (u16*)(ws + 425984);       //     32,768 B
  u16* woffb  = (u16*)(ws + 458752);       //     73,728 B
  u16* out1   = (u16*)(ws + 532480);       // 16,777,216 B  NHWC bf16
  u16* identb = (u16*)(ws + 17309696);     // 16,777,216 B  NCHW bf16

  k_init  <<<1040, 256, 0, stream>>>(w_dc, w1, w_ds, w3, w_off, wTb, wB1, w3b, woffb);
  k_fused1<<<dim3(4, 128, 4), 256, 0, stream>>>(x, wB1, s1a, t1a, s1b, t1b, b_ds, sd, td, out1, identb);
  k_dcn   <<<dim3(4, 128, 4), 512, 0, stream>>>(out1, wTb, w3b, woffb, b_off, b_dc, s2, t2,
                                                s3a, t3a, s3b, t3b, identb, (float*)d_out);
}